// Round 8
// baseline (386.066 us; speedup 1.0000x reference)
//
#include <hip/hip_runtime.h>
#include <hip/hip_fp16.h>

constexpr int N_ = 300;
constexpr int R_ = 48;
constexpr int B_ = 1048576;                        // 2^20
constexpr int NBXY = 38;                           // 8-texel tiles
constexpr int BINS_PP = NBXY * NBXY;               // 1444
constexpr int NBINS = 3 * BINS_PP;                 // 4332
constexpr int SUBS = 8;                            // one sub per XCD (blockIdx&7)
constexpr int CAP_SUB = 112;                       // mean 90.6, +2.3 sigma
constexpr int CNT_STRIDE = 16;                     // ints; 64B-padded counter cells
constexpr int BPB = 21;                            // 5376 threads >= 896*6
constexpr unsigned NWORK = NBINS * BPB;            // 90,972
constexpr unsigned GATHER_BLOCKS = 90976;          // 8*11372
constexpr unsigned XCD_CHUNK = GATHER_BLOCKS / 8;  // 11372

// ws layout (bytes)
constexpr size_t OFF_MT   = 0;                     // fp16 texture (3,300,300,48)
constexpr size_t OFF_VSUM = 25920000;              // 144 floats (+pad)
constexpr size_t OFF_CNT  = 25920640;              // int counts[SUBS*NBINS][16]
constexpr size_t OFF_REC  = 28138624;              // records
constexpr size_t END_REC32 = OFF_REC + (size_t)SUBS * NBINS * CAP_SUB * 4;  // 43,664,512 (proven)
constexpr size_t END_REC64 = OFF_REC + (size_t)SUBS * NBINS * CAP_SUB * 8;  // 59,190,400

typedef float f32x4 __attribute__((ext_vector_type(4)));
typedef unsigned long long u64;
union H8 { float4 f4; __half2 h2[4]; };

// --- init: zero padded counters + collapse line-sample analytically ---
__global__ __launch_bounds__(256) void k_init(const float* __restrict__ vec,
                                              float* __restrict__ vsum,
                                              int* __restrict__ counts) {
    int t = blockIdx.x * 256 + threadIdx.x;
    if (t < CNT_STRIDE * SUBS * NBINS) counts[t] = 0;
    if (t < 3 * R_) vsum[t] = 0.5f * (vec[t * N_ + 149] + vec[t * N_ + 150]);
}

// --- transpose matrices (3,R,N,N) f32 -> (3,N,N,R) fp16 ---
__global__ __launch_bounds__(256) void k_transpose(const float* __restrict__ mat,
                                                   __half2* __restrict__ mt2) {
    __shared__ float tile[R_][N_ + 1];
    int i = blockIdx.x / N_;
    int y = blockIdx.x - i * N_;
    const float* src = mat + ((size_t)i * R_ * N_ + y) * N_;
    for (int idx = threadIdx.x; idx < R_ * N_; idx += 256) {
        int r = idx / N_;
        int x = idx - r * N_;
        tile[r][x] = src[(size_t)r * N_ * N_ + x];
    }
    __syncthreads();
    __half2* dst = mt2 + (size_t)(i * N_ + y) * N_ * (R_ / 2);
    for (int idx = threadIdx.x; idx < N_ * (R_ / 2); idx += 256) {
        int x  = idx / (R_ / 2);
        int jj = idx - x * (R_ / 2);
        dst[idx] = __floats2half2_rn(tile[2 * jj][x], tile[2 * jj + 1][x]);
    }
}

struct BW { float w00, w01, w10, w11; int o00, o01, o10, o11; };
__device__ inline BW bilin_ix(float ix, float iy) {
    float ix0f = floorf(ix), iy0f = floorf(iy);
    float wx = ix - ix0f, wy = iy - iy0f;
    int ix0 = (int)ix0f, iy0 = (int)iy0f;
    int ix1 = ix0 + 1, iy1 = iy0 + 1;
    BW r;
    r.w00 = (1.0f - wy) * (1.0f - wx);
    r.w01 = (1.0f - wy) * wx;
    r.w10 = wy * (1.0f - wx);
    r.w11 = wy * wx;
    bool bx0 = (unsigned)ix0 < (unsigned)N_;
    bool bx1 = (unsigned)ix1 < (unsigned)N_;
    bool by0 = (unsigned)iy0 < (unsigned)N_;
    bool by1 = (unsigned)iy1 < (unsigned)N_;
    if (!(bx0 && by0)) r.w00 = 0.0f;
    if (!(bx1 && by0)) r.w01 = 0.0f;
    if (!(bx0 && by1)) r.w10 = 0.0f;
    if (!(bx1 && by1)) r.w11 = 0.0f;
    int cx0 = min(max(ix0, 0), N_ - 1), cx1 = min(max(ix1, 0), N_ - 1);
    int cy0 = min(max(iy0, 0), N_ - 1), cy1 = min(max(iy1, 0), N_ - 1);
    r.o00 = (cy0 * N_ + cx0) * R_;
    r.o01 = (cy0 * N_ + cx1) * R_;
    r.o10 = (cy1 * N_ + cx0) * R_;
    r.o11 = (cy1 * N_ + cx1) * R_;
    return r;
}

// record u64: b(20)<<44 | dixq(14)<<30 | diyq(14)<<16 | vwq(12)<<4
__device__ inline u64 enc_rec(int b, float ix, float iy, int bx, int by, float vw) {
    int dixq = (int)roundf((ix - (float)(bx * 8 - 1)) * 1024.0f);
    int diyq = (int)roundf((iy - (float)(by * 8 - 1)) * 1024.0f);
    int vwq  = (int)roundf((vw - 0.5f) * 2.0f * 4095.0f);
    return ((u64)b << 44) | ((u64)dixq << 30) | ((u64)diyq << 16) | ((u64)vwq << 4);
}
__device__ inline void dec_rec(u64 rec, int bx, int by, int& b, float& ix, float& iy, float& vw) {
    b = (int)(rec >> 44);
    int dixq = (int)((rec >> 30) & 0x3FFF);
    int diyq = (int)((rec >> 16) & 0x3FFF);
    int vwq  = (int)((rec >> 4) & 0xFFF);
    ix = (float)(bx * 8 - 1) + (float)dixq * (1.0f / 1024.0f);
    iy = (float)(by * 8 - 1) + (float)diyq * (1.0f / 1024.0f);
    vw = 0.5f + (float)vwq * (0.5f / 4095.0f);
}

// full 48-channel sample (overflow fallback; bit-identical to gather path)
__device__ inline void direct_from_rec(u64 rec, int bx, int by, int plane,
                                       const __half* __restrict__ M,
                                       const float* __restrict__ vsum,
                                       float* __restrict__ out) {
    int b; float ix, iy, vw;
    dec_rec(rec, bx, by, b, ix, iy, vw);
    BW w = bilin_ix(ix, iy);
    const __half* Mi = M + (size_t)plane * N_ * N_ * R_;
    for (int j = 0; j < 6; ++j) {
        H8 u00, u01, u10, u11;
        u00.f4 = *reinterpret_cast<const float4*>(Mi + w.o00 + 8 * j);
        u01.f4 = *reinterpret_cast<const float4*>(Mi + w.o01 + 8 * j);
        u10.f4 = *reinterpret_cast<const float4*>(Mi + w.o10 + 8 * j);
        u11.f4 = *reinterpret_cast<const float4*>(Mi + w.o11 + 8 * j);
        for (int k = 0; k < 4; ++k) {
            float2 a00 = __half22float2(u00.h2[k]);
            float2 a01 = __half22float2(u01.h2[k]);
            float2 a10 = __half22float2(u10.h2[k]);
            float2 a11 = __half22float2(u11.h2[k]);
            float r0 = fmaf(a00.x, w.w00, fmaf(a01.x, w.w01, fmaf(a10.x, w.w10, a11.x * w.w11)));
            float r1 = fmaf(a00.y, w.w00, fmaf(a01.y, w.w01, fmaf(a10.y, w.w10, a11.y * w.w11)));
            out[(size_t)b * 144 + plane * 48 + 8 * j + 2 * k]     = r0 * (vsum[plane * R_ + 8 * j + 2 * k] * vw);
            out[(size_t)b * 144 + plane * 48 + 8 * j + 2 * k + 1] = r1 * (vsum[plane * R_ + 8 * j + 2 * k + 1] * vw);
        }
    }
}

// ============ 64-bit record path (needs ws >= END_REC64) ============
__global__ __launch_bounds__(256) void k_scatter64(const float* __restrict__ coords,
                                                   int* __restrict__ counts,
                                                   u64* __restrict__ recs,
                                                   const __half* __restrict__ M,
                                                   const float* __restrict__ vsum,
                                                   float* __restrict__ out) {
    int b = blockIdx.x * 256 + threadIdx.x;
    int sub = blockIdx.x & 7;
    float c0 = coords[3 * b], c1 = coords[3 * b + 1], c2 = coords[3 * b + 2];
#pragma unroll
    for (int plane = 0; plane < 3; ++plane) {
        float xc, yc, cc;
        if (plane == 0)      { xc = c1; yc = c2; cc = c0; }
        else if (plane == 1) { xc = c2; yc = c0; cc = c1; }
        else                 { xc = c0; yc = c1; cc = c2; }
        float ix = (xc + 1.0f) * 150.0f - 0.5f;
        float iy = (yc + 1.0f) * 150.0f - 0.5f;
        int ix0 = (int)floorf(ix), iy0 = (int)floorf(iy);
        int bx = (ix0 + 1) >> 3, by = (iy0 + 1) >> 3;
        int bin = plane * BINS_PP + by * NBXY + bx;
        int cell = sub * NBINS + bin;
        float vw = 1.0f - 0.5f * fabsf(cc);
        u64 rec = enc_rec(b, ix, iy, bx, by, vw);
        int pos = atomicAdd(&counts[cell * CNT_STRIDE], 1);
        if (pos < CAP_SUB) {
            recs[(size_t)cell * CAP_SUB + pos] = rec;
        } else {
            direct_from_rec(rec, bx, by, plane, M, vsum, out);  // rare (~1.4k)
        }
    }
}

__global__ __launch_bounds__(256) void k_gather64(const int* __restrict__ counts,
                                                  const u64* __restrict__ recs,
                                                  const __half* __restrict__ M,
                                                  const float* __restrict__ vsum,
                                                  float* __restrict__ out) {
    unsigned bid  = blockIdx.x;
    unsigned vbid = (bid & 7) * XCD_CHUNK + (bid >> 3);
    if (vbid >= NWORK) return;
    unsigned bin  = vbid / BPB;
    unsigned lb   = vbid - bin * BPB;
    unsigned g = lb * 256 + threadIdx.x;                  // [0, 5376)
    unsigned slot = g / 6;                                // [0, 896)
    unsigned j = g - slot * 6;
    unsigned sub = slot / CAP_SUB;
    unsigned idx = slot - sub * CAP_SUB;
    unsigned cell = sub * NBINS + bin;
    int cnt = min(counts[cell * CNT_STRIDE], CAP_SUB);
    if ((int)idx >= cnt) return;

    int plane = bin / BINS_PP;
    int rb = bin - plane * BINS_PP;
    int by = rb / NBXY;
    int bx = rb - by * NBXY;

    u64 rec = recs[(size_t)cell * CAP_SUB + idx];
    int b; float ix, iy, vw;
    dec_rec(rec, bx, by, b, ix, iy, vw);

    BW w = bilin_ix(ix, iy);
    const __half* Mi = M + (size_t)plane * N_ * N_ * R_;
    int co = 8 * j;

    H8 u00, u01, u10, u11;
    u00.f4 = *reinterpret_cast<const float4*>(Mi + w.o00 + co);
    u01.f4 = *reinterpret_cast<const float4*>(Mi + w.o01 + co);
    u10.f4 = *reinterpret_cast<const float4*>(Mi + w.o10 + co);
    u11.f4 = *reinterpret_cast<const float4*>(Mi + w.o11 + co);

    const float4* vs4 = reinterpret_cast<const float4*>(vsum + plane * R_ + co);
    float4 vv0 = vs4[0];
    float4 vv1 = vs4[1];

    float r[8];
#pragma unroll
    for (int k = 0; k < 4; ++k) {
        float2 a00 = __half22float2(u00.h2[k]);
        float2 a01 = __half22float2(u01.h2[k]);
        float2 a10 = __half22float2(u10.h2[k]);
        float2 a11 = __half22float2(u11.h2[k]);
        r[2 * k]     = fmaf(a00.x, w.w00, fmaf(a01.x, w.w01, fmaf(a10.x, w.w10, a11.x * w.w11)));
        r[2 * k + 1] = fmaf(a00.y, w.w00, fmaf(a01.y, w.w01, fmaf(a10.y, w.w10, a11.y * w.w11)));
    }

    f32x4 s0, s1;
    s0.x = r[0] * (vv0.x * vw); s0.y = r[1] * (vv0.y * vw);
    s0.z = r[2] * (vv0.z * vw); s0.w = r[3] * (vv0.w * vw);
    s1.x = r[4] * (vv1.x * vw); s1.y = r[5] * (vv1.y * vw);
    s1.z = r[6] * (vv1.z * vw); s1.w = r[7] * (vv1.w * vw);

    float* outp = out + (size_t)b * 144 + plane * 48 + co;
    __builtin_nontemporal_store(s0, reinterpret_cast<f32x4*>(outp));
    __builtin_nontemporal_store(s1, reinterpret_cast<f32x4*>(outp) + 1);
}

// ============ 32-bit record fallback (R7 behavior, fits 43.66MB) ============
__global__ __launch_bounds__(256) void k_scatter32(const float* __restrict__ coords,
                                                   int* __restrict__ counts,
                                                   unsigned* __restrict__ recs,
                                                   const __half* __restrict__ M,
                                                   const float* __restrict__ vsum,
                                                   float* __restrict__ out) {
    int b = blockIdx.x * 256 + threadIdx.x;
    int sub = blockIdx.x & 7;
    float c0 = coords[3 * b], c1 = coords[3 * b + 1], c2 = coords[3 * b + 2];
#pragma unroll
    for (int plane = 0; plane < 3; ++plane) {
        float xc, yc, cc;
        if (plane == 0)      { xc = c1; yc = c2; cc = c0; }
        else if (plane == 1) { xc = c2; yc = c0; cc = c1; }
        else                 { xc = c0; yc = c1; cc = c2; }
        float ix = (xc + 1.0f) * 150.0f - 0.5f;
        float iy = (yc + 1.0f) * 150.0f - 0.5f;
        int ix0 = (int)floorf(ix), iy0 = (int)floorf(iy);
        int bx = (ix0 + 1) >> 3, by = (iy0 + 1) >> 3;
        int bin = plane * BINS_PP + by * NBXY + bx;
        int cell = sub * NBINS + bin;
        int pos = atomicAdd(&counts[cell * CNT_STRIDE], 1);
        if (pos < CAP_SUB) {
            recs[(size_t)cell * CAP_SUB + pos] = (unsigned)b;
        } else {
            int bxc = bx, byc = by;
            float vw = 1.0f - 0.5f * fabsf(cc);
            u64 rec = enc_rec(b, ix, iy, bxc, byc, vw);
            direct_from_rec(rec, bxc, byc, plane, M, vsum, out);
        }
    }
}

__global__ __launch_bounds__(256) void k_gather32(const float* __restrict__ coords,
                                                  const int* __restrict__ counts,
                                                  const unsigned* __restrict__ recs,
                                                  const __half* __restrict__ M,
                                                  const float* __restrict__ vsum,
                                                  float* __restrict__ out) {
    unsigned bid  = blockIdx.x;
    unsigned vbid = (bid & 7) * XCD_CHUNK + (bid >> 3);
    if (vbid >= NWORK) return;
    unsigned bin  = vbid / BPB;
    unsigned lb   = vbid - bin * BPB;
    unsigned g = lb * 256 + threadIdx.x;
    unsigned slot = g / 6;
    unsigned j = g - slot * 6;
    unsigned sub = slot / CAP_SUB;
    unsigned idx = slot - sub * CAP_SUB;
    unsigned cell = sub * NBINS + bin;
    int cnt = min(counts[cell * CNT_STRIDE], CAP_SUB);
    if ((int)idx >= cnt) return;

    int b = (int)recs[(size_t)cell * CAP_SUB + idx];
    int plane = bin / BINS_PP;

    float c0 = coords[3 * b], c1 = coords[3 * b + 1], c2 = coords[3 * b + 2];
    float xc, yc, cc;
    if (plane == 0)      { xc = c1; yc = c2; cc = c0; }
    else if (plane == 1) { xc = c2; yc = c0; cc = c1; }
    else                 { xc = c0; yc = c1; cc = c2; }

    float ix = (xc + 1.0f) * 150.0f - 0.5f;
    float iy = (yc + 1.0f) * 150.0f - 0.5f;
    BW w = bilin_ix(ix, iy);
    const __half* Mi = M + (size_t)plane * N_ * N_ * R_;
    int co = 8 * j;

    H8 u00, u01, u10, u11;
    u00.f4 = *reinterpret_cast<const float4*>(Mi + w.o00 + co);
    u01.f4 = *reinterpret_cast<const float4*>(Mi + w.o01 + co);
    u10.f4 = *reinterpret_cast<const float4*>(Mi + w.o10 + co);
    u11.f4 = *reinterpret_cast<const float4*>(Mi + w.o11 + co);

    float vw = 1.0f - 0.5f * fabsf(cc);
    const float4* vs4 = reinterpret_cast<const float4*>(vsum + plane * R_ + co);
    float4 vv0 = vs4[0];
    float4 vv1 = vs4[1];

    float r[8];
#pragma unroll
    for (int k = 0; k < 4; ++k) {
        float2 a00 = __half22float2(u00.h2[k]);
        float2 a01 = __half22float2(u01.h2[k]);
        float2 a10 = __half22float2(u10.h2[k]);
        float2 a11 = __half22float2(u11.h2[k]);
        r[2 * k]     = fmaf(a00.x, w.w00, fmaf(a01.x, w.w01, fmaf(a10.x, w.w10, a11.x * w.w11)));
        r[2 * k + 1] = fmaf(a00.y, w.w00, fmaf(a01.y, w.w01, fmaf(a10.y, w.w10, a11.y * w.w11)));
    }

    f32x4 s0, s1;
    s0.x = r[0] * (vv0.x * vw); s0.y = r[1] * (vv0.y * vw);
    s0.z = r[2] * (vv0.z * vw); s0.w = r[3] * (vv0.w * vw);
    s1.x = r[4] * (vv1.x * vw); s1.y = r[5] * (vv1.y * vw);
    s1.z = r[6] * (vv1.z * vw); s1.w = r[7] * (vv1.w * vw);

    float* outp = out + (size_t)b * 144 + plane * 48 + co;
    __builtin_nontemporal_store(s0, reinterpret_cast<f32x4*>(outp));
    __builtin_nontemporal_store(s1, reinterpret_cast<f32x4*>(outp) + 1);
}

extern "C" void kernel_launch(void* const* d_in, const int* in_sizes, int n_in,
                              void* d_out, int out_size, void* d_ws, size_t ws_size,
                              hipStream_t stream) {
    const float* coords   = (const float*)d_in[0];
    const float* matrices = (const float*)d_in[1];
    const float* vectors  = (const float*)d_in[2];
    float* out = (float*)d_out;

    __half*   mt     = (__half*)((char*)d_ws + OFF_MT);
    float*    vsum   = (float*)((char*)d_ws + OFF_VSUM);
    int*      counts = (int*)((char*)d_ws + OFF_CNT);
    void*     recs   = (void*)((char*)d_ws + OFF_REC);

    hipLaunchKernelGGL(k_init, dim3((CNT_STRIDE * SUBS * NBINS + 255) / 256), dim3(256),
                       0, stream, vectors, vsum, counts);
    hipLaunchKernelGGL(k_transpose, dim3(3 * N_), dim3(256), 0, stream,
                       matrices, (__half2*)mt);

    if (ws_size >= END_REC64) {
        hipLaunchKernelGGL(k_scatter64, dim3(B_ / 256), dim3(256), 0, stream,
                           coords, counts, (u64*)recs, mt, vsum, out);
        hipLaunchKernelGGL(k_gather64, dim3(GATHER_BLOCKS), dim3(256), 0, stream,
                           counts, (const u64*)recs, mt, vsum, out);
    } else {
        hipLaunchKernelGGL(k_scatter32, dim3(B_ / 256), dim3(256), 0, stream,
                           coords, counts, (unsigned*)recs, mt, vsum, out);
        hipLaunchKernelGGL(k_gather32, dim3(GATHER_BLOCKS), dim3(256), 0, stream,
                           coords, counts, (const unsigned*)recs, mt, vsum, out);
    }
}

// Round 9
// 235.460 us; speedup vs baseline: 1.6396x; 1.6396x over previous
//
#include <hip/hip_runtime.h>
#include <hip/hip_fp16.h>

constexpr int N_ = 300;
constexpr int R_ = 48;
constexpr int B_ = 1048576;                    // 2^20
constexpr int NCHUNK = 8;                      // y-chunks per plane (== XCD)
constexpr int NLBIN = 24;                      // 3 planes * 8 chunks
constexpr int SUBS = 8;                        // sub-cells (atomic-line spread)
constexpr int NCELL = NLBIN * SUBS;            // 192
constexpr int CAP = 16640;                     // per-cell cap; mean ~15.8k, +6 sigma
constexpr int CNT_STRIDE = 32;                 // ints; 128B-padded counter cells
constexpr int OVF_CAP = 32768;
constexpr int BPB = (CAP * 6 + 255) / 256;     // 390 blocks per cell
constexpr int VPX = 3 * SUBS * BPB;            // 9360 virtual blocks per chunk/XCD
constexpr unsigned GATHER_BLOCKS = 8 * VPX;    // 74,880

// ws layout (bytes); end 38,855,936 < 43.68MB proven
constexpr size_t OFF_MT   = 0;                 // fp16 texture (3,300,300,48) = 25,920,000
constexpr size_t OFF_VSUM = 25920000;          // 144 floats
constexpr size_t OFF_CNT  = 25920640;          // int counts[NCELL][32]
constexpr size_t OFF_OCUR = 25945216;          // overflow cursor (int)
constexpr size_t OFF_OVF  = 25945344;          // u32 ovf[OVF_CAP]
constexpr size_t OFF_REC  = 26076416;          // u32 recs[NCELL][CAP]

typedef float f32x4 __attribute__((ext_vector_type(4)));
union H8 { float4 f4; __half2 h2[4]; };

// --- prep: transpose (blocks 0..899) + vsum/zero-counters (block 900) ---
__global__ __launch_bounds__(256) void k_prep(const float* __restrict__ mat,
                                              const float* __restrict__ vec,
                                              __half2* __restrict__ mt2,
                                              float* __restrict__ vsum,
                                              int* __restrict__ counts,
                                              int* __restrict__ ocur) {
    if (blockIdx.x == 900) {
        int t = threadIdx.x;
        if (t < 3 * R_) vsum[t] = 0.5f * (vec[t * N_ + 149] + vec[t * N_ + 150]);
        for (int k = t; k < NCELL * CNT_STRIDE; k += 256) counts[k] = 0;
        if (t == 255) *ocur = 0;
        return;
    }
    __shared__ float tile[R_][N_ + 1];
    int i = blockIdx.x / N_;
    int y = blockIdx.x - i * N_;
    const float* src = mat + ((size_t)i * R_ * N_ + y) * N_;
    for (int idx = threadIdx.x; idx < R_ * N_; idx += 256) {
        int r = idx / N_;
        int x = idx - r * N_;
        tile[r][x] = src[(size_t)r * N_ * N_ + x];
    }
    __syncthreads();
    __half2* dst = mt2 + (size_t)(i * N_ + y) * N_ * (R_ / 2);
    for (int idx = threadIdx.x; idx < N_ * (R_ / 2); idx += 256) {
        int x  = idx / (R_ / 2);
        int jj = idx - x * (R_ / 2);
        dst[idx] = __floats2half2_rn(tile[2 * jj][x], tile[2 * jj + 1][x]);
    }
}

struct BW { float w00, w01, w10, w11; int o00, o01, o10, o11; };
__device__ inline BW bilin_ix(float ix, float iy) {
    float ix0f = floorf(ix), iy0f = floorf(iy);
    float wx = ix - ix0f, wy = iy - iy0f;
    int ix0 = (int)ix0f, iy0 = (int)iy0f;
    int ix1 = ix0 + 1, iy1 = iy0 + 1;
    BW r;
    r.w00 = (1.0f - wy) * (1.0f - wx);
    r.w01 = (1.0f - wy) * wx;
    r.w10 = wy * (1.0f - wx);
    r.w11 = wy * wx;
    bool bx0 = (unsigned)ix0 < (unsigned)N_;
    bool bx1 = (unsigned)ix1 < (unsigned)N_;
    bool by0 = (unsigned)iy0 < (unsigned)N_;
    bool by1 = (unsigned)iy1 < (unsigned)N_;
    if (!(bx0 && by0)) r.w00 = 0.0f;
    if (!(bx1 && by0)) r.w01 = 0.0f;
    if (!(bx0 && by1)) r.w10 = 0.0f;
    if (!(bx1 && by1)) r.w11 = 0.0f;
    int cx0 = min(max(ix0, 0), N_ - 1), cx1 = min(max(ix1, 0), N_ - 1);
    int cy0 = min(max(iy0, 0), N_ - 1), cy1 = min(max(iy1, 0), N_ - 1);
    r.o00 = (cy0 * N_ + cx0) * R_;
    r.o01 = (cy0 * N_ + cx1) * R_;
    r.o10 = (cy1 * N_ + cx0) * R_;
    r.o11 = (cy1 * N_ + cx1) * R_;
    return r;
}

__device__ inline void plane_xy(int plane, float c0, float c1, float c2,
                                float& xc, float& yc, float& cc) {
    if (plane == 0)      { xc = c1; yc = c2; cc = c0; }
    else if (plane == 1) { xc = c2; yc = c0; cc = c1; }
    else                 { xc = c0; yc = c1; cc = c2; }
}

// --- scatter: LDS-aggregated binning. 24 coarse bins (plane x y-chunk);
// 24 global atomics PER BLOCK (98k total, vs 3.1M per-sample) -- the R7
// scatter's cost was raw global-atomic count, not line conflicts.
__global__ __launch_bounds__(256) void k_scatter(const float* __restrict__ coords,
                                                 int* __restrict__ counts,
                                                 unsigned* __restrict__ recs,
                                                 int* __restrict__ ocur,
                                                 unsigned* __restrict__ ovf) {
    __shared__ int lcnt[NLBIN];
    __shared__ int lbase[NLBIN];
    int tid = threadIdx.x;
    if (tid < NLBIN) lcnt[tid] = 0;
    __syncthreads();

    int b = blockIdx.x * 256 + tid;
    int sub = blockIdx.x & 7;
    float c0 = coords[3 * b], c1 = coords[3 * b + 1], c2 = coords[3 * b + 2];

    int lbin[3], lpos[3];
#pragma unroll
    for (int plane = 0; plane < 3; ++plane) {
        float xc, yc, cc;
        plane_xy(plane, c0, c1, c2, xc, yc, cc);
        float iy = (yc + 1.0f) * 150.0f - 0.5f;
        int row = (int)floorf(iy) + 1;               // [0, 300]
        int chunk = row * 8 / 301;                   // [0, 7]
        lbin[plane] = plane * NCHUNK + chunk;
        lpos[plane] = atomicAdd(&lcnt[lbin[plane]], 1);
    }
    __syncthreads();
    if (tid < NLBIN) {
        int cell = tid * SUBS + sub;
        lbase[tid] = atomicAdd(&counts[cell * CNT_STRIDE], lcnt[tid]);
    }
    __syncthreads();
#pragma unroll
    for (int plane = 0; plane < 3; ++plane) {
        int pos = lbase[lbin[plane]] + lpos[plane];
        int cell = lbin[plane] * SUBS + sub;
        if (pos < CAP) {
            recs[(size_t)cell * CAP + pos] = (unsigned)b;
        } else {
            int o = atomicAdd(ocur, 1);
            if (o < OVF_CAP) ovf[o] = (unsigned)b | ((unsigned)plane << 20);
        }
    }
}

// --- gather: blocks of chunk c land on XCD c (bid&7); per-XCD texture slice
// = 3 planes x ~1.1MB chunk footprint ~= 3.4MB -> L2-resident.
__global__ __launch_bounds__(256) void k_gather(const float* __restrict__ coords,
                                                const int* __restrict__ counts,
                                                const unsigned* __restrict__ recs,
                                                const __half* __restrict__ M,
                                                const float* __restrict__ vsum,
                                                float* __restrict__ out) {
    unsigned bid = blockIdx.x;
    unsigned chunk = bid & 7;
    unsigned v = bid >> 3;                     // [0, 9360)
    unsigned plane = v / (SUBS * BPB);         // /3120
    unsigned r0 = v - plane * (SUBS * BPB);
    unsigned sub = r0 / BPB;                   // /390
    unsigned lb  = r0 - sub * BPB;
    unsigned cell = (plane * NCHUNK + chunk) * SUBS + sub;
    int cnt = min(counts[cell * CNT_STRIDE], CAP);
    unsigned g = lb * 256 + threadIdx.x;
    unsigned slot = g / 6;
    unsigned j = g - slot * 6;
    if ((int)slot >= cnt) return;

    int b = (int)recs[(size_t)cell * CAP + slot];

    float c0 = coords[3 * b], c1 = coords[3 * b + 1], c2 = coords[3 * b + 2];
    float xc, yc, cc;
    plane_xy((int)plane, c0, c1, c2, xc, yc, cc);

    float ix = (xc + 1.0f) * 150.0f - 0.5f;
    float iy = (yc + 1.0f) * 150.0f - 0.5f;
    BW w = bilin_ix(ix, iy);
    const __half* Mi = M + (size_t)plane * N_ * N_ * R_;
    int co = 8 * j;

    H8 u00, u01, u10, u11;
    u00.f4 = *reinterpret_cast<const float4*>(Mi + w.o00 + co);
    u01.f4 = *reinterpret_cast<const float4*>(Mi + w.o01 + co);
    u10.f4 = *reinterpret_cast<const float4*>(Mi + w.o10 + co);
    u11.f4 = *reinterpret_cast<const float4*>(Mi + w.o11 + co);

    float vw = 1.0f - 0.5f * fabsf(cc);
    const float4* vs4 = reinterpret_cast<const float4*>(vsum + plane * R_ + co);
    float4 vv0 = vs4[0];
    float4 vv1 = vs4[1];

    float r[8];
#pragma unroll
    for (int k = 0; k < 4; ++k) {
        float2 a00 = __half22float2(u00.h2[k]);
        float2 a01 = __half22float2(u01.h2[k]);
        float2 a10 = __half22float2(u10.h2[k]);
        float2 a11 = __half22float2(u11.h2[k]);
        r[2 * k]     = fmaf(a00.x, w.w00, fmaf(a01.x, w.w01, fmaf(a10.x, w.w10, a11.x * w.w11)));
        r[2 * k + 1] = fmaf(a00.y, w.w00, fmaf(a01.y, w.w01, fmaf(a10.y, w.w10, a11.y * w.w11)));
    }

    f32x4 s0, s1;
    s0.x = r[0] * (vv0.x * vw); s0.y = r[1] * (vv0.y * vw);
    s0.z = r[2] * (vv0.z * vw); s0.w = r[3] * (vv0.w * vw);
    s1.x = r[4] * (vv1.x * vw); s1.y = r[5] * (vv1.y * vw);
    s1.z = r[6] * (vv1.z * vw); s1.w = r[7] * (vv1.w * vw);

    float* outp = out + (size_t)b * 144 + plane * 48 + co;
    __builtin_nontemporal_store(s0, reinterpret_cast<f32x4*>(outp));
    __builtin_nontemporal_store(s1, reinterpret_cast<f32x4*>(outp) + 1);
}

// --- overflow cleanup: full 48-channel direct samples (rare) ---
__global__ __launch_bounds__(256) void k_overflow(const float* __restrict__ coords,
                                                  const int* __restrict__ ocur,
                                                  const unsigned* __restrict__ ovf,
                                                  const __half* __restrict__ M,
                                                  const float* __restrict__ vsum,
                                                  float* __restrict__ out) {
    int cnt = min(*ocur, OVF_CAP);
    for (int t = blockIdx.x * 256 + threadIdx.x; t < cnt; t += gridDim.x * 256) {
        unsigned rec = ovf[t];
        int b = (int)(rec & 0xFFFFF);
        int plane = (int)(rec >> 20);
        float c0 = coords[3 * b], c1 = coords[3 * b + 1], c2 = coords[3 * b + 2];
        float xc, yc, cc;
        plane_xy(plane, c0, c1, c2, xc, yc, cc);
        float ix = (xc + 1.0f) * 150.0f - 0.5f;
        float iy = (yc + 1.0f) * 150.0f - 0.5f;
        BW w = bilin_ix(ix, iy);
        float vw = 1.0f - 0.5f * fabsf(cc);
        const __half* Mi = M + (size_t)plane * N_ * N_ * R_;
        for (int j = 0; j < 6; ++j) {
            H8 u00, u01, u10, u11;
            u00.f4 = *reinterpret_cast<const float4*>(Mi + w.o00 + 8 * j);
            u01.f4 = *reinterpret_cast<const float4*>(Mi + w.o01 + 8 * j);
            u10.f4 = *reinterpret_cast<const float4*>(Mi + w.o10 + 8 * j);
            u11.f4 = *reinterpret_cast<const float4*>(Mi + w.o11 + 8 * j);
            for (int k = 0; k < 4; ++k) {
                float2 a00 = __half22float2(u00.h2[k]);
                float2 a01 = __half22float2(u01.h2[k]);
                float2 a10 = __half22float2(u10.h2[k]);
                float2 a11 = __half22float2(u11.h2[k]);
                float r0 = fmaf(a00.x, w.w00, fmaf(a01.x, w.w01, fmaf(a10.x, w.w10, a11.x * w.w11)));
                float r1 = fmaf(a00.y, w.w00, fmaf(a01.y, w.w01, fmaf(a10.y, w.w10, a11.y * w.w11)));
                out[(size_t)b * 144 + plane * 48 + 8 * j + 2 * k]     = r0 * (vsum[plane * R_ + 8 * j + 2 * k] * vw);
                out[(size_t)b * 144 + plane * 48 + 8 * j + 2 * k + 1] = r1 * (vsum[plane * R_ + 8 * j + 2 * k + 1] * vw);
            }
        }
    }
}

extern "C" void kernel_launch(void* const* d_in, const int* in_sizes, int n_in,
                              void* d_out, int out_size, void* d_ws, size_t ws_size,
                              hipStream_t stream) {
    const float* coords   = (const float*)d_in[0];
    const float* matrices = (const float*)d_in[1];
    const float* vectors  = (const float*)d_in[2];
    float* out = (float*)d_out;

    __half*   mt     = (__half*)((char*)d_ws + OFF_MT);
    float*    vsum   = (float*)((char*)d_ws + OFF_VSUM);
    int*      counts = (int*)((char*)d_ws + OFF_CNT);
    int*      ocur   = (int*)((char*)d_ws + OFF_OCUR);
    unsigned* ovf    = (unsigned*)((char*)d_ws + OFF_OVF);
    unsigned* recs   = (unsigned*)((char*)d_ws + OFF_REC);

    hipLaunchKernelGGL(k_prep, dim3(901), dim3(256), 0, stream,
                       matrices, vectors, (__half2*)mt, vsum, counts, ocur);
    hipLaunchKernelGGL(k_scatter, dim3(B_ / 256), dim3(256), 0, stream,
                       coords, counts, recs, ocur, ovf);
    hipLaunchKernelGGL(k_gather, dim3(GATHER_BLOCKS), dim3(256), 0, stream,
                       coords, counts, recs, mt, vsum, out);
    hipLaunchKernelGGL(k_overflow, dim3(64), dim3(256), 0, stream,
                       coords, ocur, ovf, mt, vsum, out);
}

// Round 10
// 229.432 us; speedup vs baseline: 1.6827x; 1.0263x over previous
//
#include <hip/hip_runtime.h>
#include <hip/hip_fp16.h>

constexpr int N_ = 300;
constexpr int R_ = 48;
constexpr int B_ = 1048576;                    // 2^20
constexpr int NBIN3 = 64;                      // 4x4x4 bins over (c0,c1,c2) row-chunks
constexpr int SUBS = 8;                        // sub-cells (XCD-private counter lines)
constexpr int NCELL = NBIN3 * SUBS;            // 512
constexpr int CAP = 2304;                      // per-cell; mean 2048, ~+4.5 sigma
constexpr int CNT_STRIDE = 32;                 // ints; 128B-padded counter cells
constexpr int OVF_CAP = 262144;
constexpr int BPB = CAP * 6 / 256;             // 54 blocks per cell
constexpr unsigned GB_MAIN = NCELL * BPB;      // 27,648 = 8 * 3456
constexpr unsigned XCHUNK = GB_MAIN / 8;       // 3456
constexpr unsigned OVF_BLOCKS = 64;
constexpr unsigned GRID_GATHER = GB_MAIN + OVF_BLOCKS;

// ws layout (bytes); end 31,753,472 << 43,681,920 proven
constexpr size_t OFF_MT   = 0;                 // fp16 texture (3,300,300,48) = 25,920,000
constexpr size_t OFF_VSUM = 25920000;          // 144 floats (+pad)
constexpr size_t OFF_CNT  = 25920640;          // int counts[NCELL][32]
constexpr size_t OFF_OCUR = 25986176;          // overflow cursor
constexpr size_t OFF_OVF  = 25986304;          // u32 ovf[OVF_CAP] (b only)
constexpr size_t OFF_REC  = 27034880;          // u32 recs[NCELL][CAP] (b only)

typedef float f32x4 __attribute__((ext_vector_type(4)));
union H8 { float4 f4; __half2 h2[4]; };

// --- prep: transpose (blocks 0..899) + vsum/zero-counters (block 900) ---
__global__ __launch_bounds__(256) void k_prep(const float* __restrict__ mat,
                                              const float* __restrict__ vec,
                                              __half2* __restrict__ mt2,
                                              float* __restrict__ vsum,
                                              int* __restrict__ counts,
                                              int* __restrict__ ocur) {
    if (blockIdx.x == 900) {
        int t = threadIdx.x;
        if (t < 3 * R_) vsum[t] = 0.5f * (vec[t * N_ + 149] + vec[t * N_ + 150]);
        for (int k = t; k < NCELL * CNT_STRIDE; k += 256) counts[k] = 0;
        if (t == 0) *ocur = 0;
        return;
    }
    __shared__ float tile[R_][N_ + 1];
    int i = blockIdx.x / N_;
    int y = blockIdx.x - i * N_;
    const float* src = mat + ((size_t)i * R_ * N_ + y) * N_;
    for (int idx = threadIdx.x; idx < R_ * N_; idx += 256) {
        int r = idx / N_;
        int x = idx - r * N_;
        tile[r][x] = src[(size_t)r * N_ * N_ + x];
    }
    __syncthreads();
    __half2* dst = mt2 + (size_t)(i * N_ + y) * N_ * (R_ / 2);
    for (int idx = threadIdx.x; idx < N_ * (R_ / 2); idx += 256) {
        int x  = idx / (R_ / 2);
        int jj = idx - x * (R_ / 2);
        dst[idx] = __floats2half2_rn(tile[2 * jj][x], tile[2 * jj + 1][x]);
    }
}

struct BW { float w00, w01, w10, w11; int o00, o01, o10, o11; };
__device__ inline BW bilin_ix(float ix, float iy) {
    float ix0f = floorf(ix), iy0f = floorf(iy);
    float wx = ix - ix0f, wy = iy - iy0f;
    int ix0 = (int)ix0f, iy0 = (int)iy0f;
    int ix1 = ix0 + 1, iy1 = iy0 + 1;
    BW r;
    r.w00 = (1.0f - wy) * (1.0f - wx);
    r.w01 = (1.0f - wy) * wx;
    r.w10 = wy * (1.0f - wx);
    r.w11 = wy * wx;
    bool bx0 = (unsigned)ix0 < (unsigned)N_;
    bool bx1 = (unsigned)ix1 < (unsigned)N_;
    bool by0 = (unsigned)iy0 < (unsigned)N_;
    bool by1 = (unsigned)iy1 < (unsigned)N_;
    if (!(bx0 && by0)) r.w00 = 0.0f;
    if (!(bx1 && by0)) r.w01 = 0.0f;
    if (!(bx0 && by1)) r.w10 = 0.0f;
    if (!(bx1 && by1)) r.w11 = 0.0f;
    int cx0 = min(max(ix0, 0), N_ - 1), cx1 = min(max(ix1, 0), N_ - 1);
    int cy0 = min(max(iy0, 0), N_ - 1), cy1 = min(max(iy1, 0), N_ - 1);
    r.o00 = (cy0 * N_ + cx0) * R_;
    r.o01 = (cy0 * N_ + cx1) * R_;
    r.o10 = (cy1 * N_ + cx0) * R_;
    r.o11 = (cy1 * N_ + cx1) * R_;
    return r;
}

__device__ inline void plane_xy(int plane, float c0, float c1, float c2,
                                float& xc, float& yc, float& cc) {
    if (plane == 0)      { xc = c1; yc = c2; cc = c0; }
    else if (plane == 1) { xc = c2; yc = c0; cc = c1; }
    else                 { xc = c0; yc = c1; cc = c2; }
}

// one plane's channels [8j, 8j+8) for sample b — shared by gather & overflow
// so both paths are bit-identical (determinism under atomic reordering).
__device__ inline void sample8(int plane, int j, int b, float c0, float c1, float c2,
                               const __half* __restrict__ M,
                               const float* __restrict__ vsum,
                               float* __restrict__ out) {
    float xc, yc, cc;
    plane_xy(plane, c0, c1, c2, xc, yc, cc);
    float ix = (xc + 1.0f) * 150.0f - 0.5f;
    float iy = (yc + 1.0f) * 150.0f - 0.5f;
    BW w = bilin_ix(ix, iy);
    const __half* Mi = M + (size_t)plane * N_ * N_ * R_;
    int co = 8 * j;

    H8 u00, u01, u10, u11;
    u00.f4 = *reinterpret_cast<const float4*>(Mi + w.o00 + co);
    u01.f4 = *reinterpret_cast<const float4*>(Mi + w.o01 + co);
    u10.f4 = *reinterpret_cast<const float4*>(Mi + w.o10 + co);
    u11.f4 = *reinterpret_cast<const float4*>(Mi + w.o11 + co);

    float vw = 1.0f - 0.5f * fabsf(cc);
    const float4* vs4 = reinterpret_cast<const float4*>(vsum + plane * R_ + co);
    float4 vv0 = vs4[0];
    float4 vv1 = vs4[1];

    float r[8];
#pragma unroll
    for (int k = 0; k < 4; ++k) {
        float2 a00 = __half22float2(u00.h2[k]);
        float2 a01 = __half22float2(u01.h2[k]);
        float2 a10 = __half22float2(u10.h2[k]);
        float2 a11 = __half22float2(u11.h2[k]);
        r[2 * k]     = fmaf(a00.x, w.w00, fmaf(a01.x, w.w01, fmaf(a10.x, w.w10, a11.x * w.w11)));
        r[2 * k + 1] = fmaf(a00.y, w.w00, fmaf(a01.y, w.w01, fmaf(a10.y, w.w10, a11.y * w.w11)));
    }

    f32x4 s0, s1;
    s0.x = r[0] * (vv0.x * vw); s0.y = r[1] * (vv0.y * vw);
    s0.z = r[2] * (vv0.z * vw); s0.w = r[3] * (vv0.w * vw);
    s1.x = r[4] * (vv1.x * vw); s1.y = r[5] * (vv1.y * vw);
    s1.z = r[6] * (vv1.z * vw); s1.w = r[7] * (vv1.w * vw);

    float* outp = out + (size_t)b * 144 + plane * 48 + co;
    __builtin_nontemporal_store(s0, reinterpret_cast<f32x4*>(outp));
    __builtin_nontemporal_store(s1, reinterpret_cast<f32x4*>(outp) + 1);
}

__device__ inline int row_chunk(float c) {
    float i = (c + 1.0f) * 150.0f - 0.5f;
    int row = (int)floorf(i) + 1;            // [0, 300]
    return (row * 4) / 301;                  // [0, 3]
}

// --- scatter: ONE record per b, binned by the (c0,c1,c2) chunk triple.
// 1 LDS atomic per sample; 64 global atomics per block (262k total).
__global__ __launch_bounds__(256) void k_scatter(const float* __restrict__ coords,
                                                 int* __restrict__ counts,
                                                 unsigned* __restrict__ recs,
                                                 int* __restrict__ ocur,
                                                 unsigned* __restrict__ ovf) {
    __shared__ int lcnt[NBIN3];
    __shared__ int lbase[NBIN3];
    int tid = threadIdx.x;
    if (tid < NBIN3) lcnt[tid] = 0;
    __syncthreads();

    int b = blockIdx.x * 256 + tid;
    int sub = blockIdx.x & 7;                  // = XCD under round-robin dispatch
    float c0 = coords[3 * b], c1 = coords[3 * b + 1], c2 = coords[3 * b + 2];
    int bin = row_chunk(c0) * 16 + row_chunk(c1) * 4 + row_chunk(c2);
    int lpos = atomicAdd(&lcnt[bin], 1);
    __syncthreads();
    if (tid < NBIN3) {
        int cell = tid * SUBS + sub;
        lbase[tid] = atomicAdd(&counts[cell * CNT_STRIDE], lcnt[tid]);
    }
    __syncthreads();
    int pos = lbase[bin] + lpos;
    int cell = bin * SUBS + sub;
    if (pos < CAP) {
        recs[(size_t)cell * CAP + pos] = (unsigned)b;
    } else {
        int o = atomicAdd(ocur, 1);
        if (o < OVF_CAP) ovf[o] = (unsigned)b;
    }
}

// --- gather (+fused overflow): 54 blocks per cell. Bin footprint = 3 planes
// x ~77x77 texels ~= 1.7MB -> L2-resident. Each XCD owns 8 consecutive bins.
// One record covers ALL 3 planes: coords read once, 576B contiguous out.
__global__ __launch_bounds__(256) void k_gather(const float* __restrict__ coords,
                                                const int* __restrict__ counts,
                                                const unsigned* __restrict__ recs,
                                                const int* __restrict__ ocur,
                                                const unsigned* __restrict__ ovf,
                                                const __half* __restrict__ M,
                                                const float* __restrict__ vsum,
                                                float* __restrict__ out) {
    unsigned bid = blockIdx.x;
    if (bid >= GB_MAIN) {
        // overflow path: full 144-channel samples, grid-stride
        int cnt = min(*ocur, OVF_CAP);
        for (int t = (bid - GB_MAIN) * 256 + threadIdx.x; t < cnt; t += OVF_BLOCKS * 256) {
            int b = (int)ovf[t];
            float c0 = coords[3 * b], c1 = coords[3 * b + 1], c2 = coords[3 * b + 2];
#pragma unroll
            for (int p = 0; p < 3; ++p)
                for (int j = 0; j < 6; ++j)
                    sample8(p, j, b, c0, c1, c2, M, vsum, out);
        }
        return;
    }
    unsigned vbid = (bid & 7) * XCHUNK + (bid >> 3);   // cells chunked per XCD
    unsigned cell = vbid / BPB;
    unsigned lb   = vbid - cell * BPB;
    unsigned g = lb * 256 + threadIdx.x;               // [0, 13824)
    unsigned slot = g / 6;                             // [0, 2304)
    unsigned j = g - slot * 6;
    int cnt = min(counts[cell * CNT_STRIDE], CAP);
    if ((int)slot >= cnt) return;

    int b = (int)recs[(size_t)cell * CAP + slot];
    float c0 = coords[3 * b], c1 = coords[3 * b + 1], c2 = coords[3 * b + 2];
#pragma unroll
    for (int p = 0; p < 3; ++p)
        sample8(p, (int)j, b, c0, c1, c2, M, vsum, out);
}

extern "C" void kernel_launch(void* const* d_in, const int* in_sizes, int n_in,
                              void* d_out, int out_size, void* d_ws, size_t ws_size,
                              hipStream_t stream) {
    const float* coords   = (const float*)d_in[0];
    const float* matrices = (const float*)d_in[1];
    const float* vectors  = (const float*)d_in[2];
    float* out = (float*)d_out;

    __half*   mt     = (__half*)((char*)d_ws + OFF_MT);
    float*    vsum   = (float*)((char*)d_ws + OFF_VSUM);
    int*      counts = (int*)((char*)d_ws + OFF_CNT);
    int*      ocur   = (int*)((char*)d_ws + OFF_OCUR);
    unsigned* ovf    = (unsigned*)((char*)d_ws + OFF_OVF);
    unsigned* recs   = (unsigned*)((char*)d_ws + OFF_REC);

    hipLaunchKernelGGL(k_prep, dim3(901), dim3(256), 0, stream,
                       matrices, vectors, (__half2*)mt, vsum, counts, ocur);
    hipLaunchKernelGGL(k_scatter, dim3(B_ / 256), dim3(256), 0, stream,
                       coords, counts, recs, ocur, ovf);
    hipLaunchKernelGGL(k_gather, dim3(GRID_GATHER), dim3(256), 0, stream,
                       coords, counts, recs, ocur, ovf, mt, vsum, out);
}